// Round 12
// baseline (255.548 us; speedup 1.0000x reference)
//
#include <hip/hip_runtime.h>

// TemporalLogicLayer R12: fuse finalize into main (per-t split-K fixup),
// coalesced PW prep. 2 dispatches total.
// out[b,t,o] = max_{s>=t} sigmoid(5*(relu(relu([cummax(P[t..s])|P[s]]W1+b1)W2+b2)W3+b3))
//
// R11 post-mortem: main ~150 us is invariant to resident-block capacity
// (1/2/4 blocks/CU -> 166/149/155 us) — per-item latency chain is the floor.
// The reliable remaining target: per-dispatch overhead ~20-25 us (3 dispatches
// = ~70 us of gap). R12:
// - finalize fused into tll_main via R9's per-t arrival counter + last-arriver
//   fixup (correctness-proven in R9; R9's regression was its global spin
//   barriers, NOT the fixup). ~1400 total atomicAdds. tctr zeroed by prep
//   (stream order) -> no memset dispatch. 3 dispatches -> 2.
// - prep PW phase: R11 issued 288 stride-132 uncoalesced f32 loads per wave;
//   now cooperative coalesced load + LDS transpose (w1s[n][k], stride 130,
//   conflict-free) + b128 fragment reads.
// Main item loop byte-identical to R11 (64 VGPR, LDS overlay 38944 B).

#define TT 128
#define BB 32
#define DD 128
#define OO 64
#define NP 144
#define HSTR2 152
#define KSLOT 17
#define NBLK 1024
#define ZOFF (128*HSTR2)                            // zero strip, f16 offset 19456

typedef __attribute__((ext_vector_type(8))) _Float16 half8;
typedef __attribute__((ext_vector_type(4))) _Float16 half4;
typedef __attribute__((ext_vector_type(4))) float f32x4;

// ws layout (bytes)
#define W1T_OFF 0                                   // f16 [144][128] (K<128 half)
#define W2T_OFF (W1T_OFF + 144*128*2)               // f16 [144][160]
#define W3T_OFF (W2T_OFF + 144*160*2)               // f16 [64][160]
#define B1P_OFF (W3T_OFF + 64*160*2)                // f32 [144]
#define B2P_OFF (B1P_OFF + 144*4)                   // f32 [144]
#define PW_OFF  (B2P_OFF + 144*4)                   // f16 [4096][144]
#define PF_OFF  (PW_OFF + 4096*144*2)               // f16 [32][128][128]
#define SLOT_OFF (PF_OFF + 32*128*128*2)            // f16 [128][KSLOT][32][64]
#define CTR_OFF  (SLOT_OFF + 128*KSLOT*2048*2)      // u32 tctr[128]

#define MFMA(A, B, C) __builtin_amdgcn_mfma_f32_16x16x32_f16((A), (B), (C), 0, 0, 0)

__device__ __forceinline__ half8 h8max(half8 a, half8 b) {
    half8 r;
    #pragma unroll
    for (int i = 0; i < 8; ++i) r[i] = (a[i] > b[i]) ? a[i] : b[i];
    return r;
}

// largest bid with range_start(bid) = (bid*33)>>4 <= it   (1024-block partition)
__device__ __forceinline__ int bid_of(int it) {
    int bb = (16 * it) / 33;
    while ((((bb + 1) * 33) >> 4) <= it) ++bb;
    while (((bb * 33) >> 4) > it) --bb;
    return bb;
}

// ---------- prep (240 blocks x 256) ----------
__global__ void tll_prep(const float* __restrict__ P,
                         const float* __restrict__ W1, const float* __restrict__ b1,
                         const float* __restrict__ W2, const float* __restrict__ b2,
                         const float* __restrict__ W3, char* __restrict__ ws) {
    __shared__ _Float16 w1s[144 * 130];             // 37440 B (PW blocks only)
    const int blk = blockIdx.x, tid = threadIdx.x;
    if (blk < 144) {
        _Float16* W1t = (_Float16*)(ws + W1T_OFF);
        _Float16* W2t = (_Float16*)(ws + W2T_OFF);
        _Float16* W3t = (_Float16*)(ws + W3T_OFF);
        float*    b1p = (float*)(ws + B1P_OFF);
        float*    b2p = (float*)(ws + B2P_OFF);
        int idx = blk * 256 + tid;
        if (idx < 144*128) {                        // W1t[n][k] = W1[k][n], k<128
            int n = idx >> 7, k = idx & 127;
            W1t[idx] = (_Float16)((n < 132) ? W1[k*132 + n] : 0.f);
        }
        if (idx < 144*160) {                        // W2t[n][k] = W2[k][n]
            int n = idx / 160, k = idx - n*160;
            W2t[idx] = (_Float16)((n < 132 && k < 132) ? W2[k*132 + n] : 0.f);
        }
        if (idx < 64*160) {                         // W3t[o][k] = W3[k][o]
            int o = idx / 160, k = idx - o*160;
            W3t[idx] = (_Float16)((k < 132) ? W3[k*64 + o] : 0.f);
        }
        if (idx < 144) {
            b1p[idx] = (idx < 132) ? b1[idx] : 0.f;
            b2p[idx] = (idx < 132) ? b2[idx] : 0.f;
        }
    } else if (blk < 208) {
        // PW[row][n] = P[row] @ W1[128:256, :], row = s*32+b.
        // coalesced W1-row loads -> LDS transpose w1s[n*130+k] (stride 130:
        // consecutive n -> +65 dwords -> all banks, conflict-free).
        _Float16* PW = (_Float16*)(ws + PW_OFF);
        const int blkp = blk - 144;
        for (int i = tid; i < 128*132; i += 256) {  // i: k-major, n consecutive
            int k = i / 132, n = i - k*132;
            w1s[n*130 + k] = (_Float16)W1[(128 + k)*132 + n];
        }
        for (int i = tid; i < 12*130; i += 256) {   // zero pad n = 132..143
            int n = 132 + i/130, k = i - (i/130)*130;
            w1s[n*130 + k] = (_Float16)0.f;
        }
        __syncthreads();
        const int w = tid >> 6, lane = tid & 63;
        const int ln = lane & 15, q = lane >> 4;
        const int row = (blkp*4 + w)*16 + ln;       // 0..4095
        const int b_ = row & 31, s_ = row >> 5;
        const float* pp = P + b_*(TT*DD) + s_*DD;
        half8 Bf[4];
        #pragma unroll
        for (int kst = 0; kst < 4; ++kst) {
            f32x4 p0 = *(const f32x4*)(pp + kst*32 + q*8);
            f32x4 p1 = *(const f32x4*)(pp + kst*32 + q*8 + 4);
            half8 h;
            #pragma unroll
            for (int i = 0; i < 4; ++i) { h[i] = (_Float16)p0[i]; h[4+i] = (_Float16)p1[i]; }
            Bf[kst] = h;
        }
        for (int mt = 0; mt < 9; ++mt) {
            f32x4 acc = (f32x4){0.f, 0.f, 0.f, 0.f};
            #pragma unroll
            for (int kst = 0; kst < 4; ++kst) {
                half8 A = *(const half8*)&w1s[(mt*16 + ln)*130 + kst*32 + q*8];
                acc = MFMA(A, Bf[kst], acc);
            }
            half4 hv;
            #pragma unroll
            for (int i = 0; i < 4; ++i) hv[i] = (_Float16)acc[i];
            *(half4*)(PW + (size_t)row*NP + mt*16 + q*4) = hv;
        }
    } else {
        // Pf[b] = f16(P[b]); block 208 also zeroes the per-t arrival counters
        _Float16* Pf = (_Float16*)(ws + PF_OFF);
        const int b = blk - 208;
        if (b == 0 && tid < 128) ((unsigned*)(ws + CTR_OFF))[tid] = 0u;
        const f32x4* src = (const f32x4*)(P + (size_t)b * TT * DD);
        half4* dst = (half4*)(Pf + (size_t)b * TT * DD);
        for (int i = tid; i < TT*DD/4; i += 256) {
            f32x4 v = src[i];
            half4 h;
            #pragma unroll
            for (int j = 0; j < 4; ++j) h[j] = (_Float16)v[j];
            dst[i] = h;
        }
    }
}

// ---------- main (finalize fused via per-t fixup) ----------
__global__ __launch_bounds__(512, 4) void tll_main(
    const float* __restrict__ b3, char* __restrict__ ws, float* __restrict__ out)
{
    extern __shared__ char smem[];
    _Float16* hB  = (_Float16*)smem;                // overlay: cmx[128][128]sw /
    _Float16* cmx = hB;                             //          h[128][152]
    const _Float16* zstrip = hB + ZOFF;             // 32 B zeros (kst=4, q>=2)

    const _Float16* W1t = (const _Float16*)(ws + W1T_OFF);
    const _Float16* W2t = (const _Float16*)(ws + W2T_OFF);
    const _Float16* W3t = (const _Float16*)(ws + W3T_OFF);
    const float*    b1p = (const float*)(ws + B1P_OFF);
    const float*    b2p = (const float*)(ws + B2P_OFF);
    const _Float16* PW  = (const _Float16*)(ws + PW_OFF);
    const _Float16* Pf  = (const _Float16*)(ws + PF_OFF);
    _Float16*       slots = (_Float16*)(ws + SLOT_OFF);
    unsigned*       tctr  = (unsigned*)(ws + CTR_OFF);

    const int tid = threadIdx.x, w = tid >> 6, lane = tid & 63;
    const int ln = lane & 15, q = lane >> 4;
    const int fg = w >> 1, rg = w & 1;              // 4 f-groups x 2 r-groups
    const bool has3 = (fg == 0);                    // f-tiles (3,2,2,2) of 9
    const int fb = (fg == 0) ? 0 : (16 + 32*fg);    // 0,48,80,112
    const int f0A = fb, f0B = fb + 16, f0C = fb + 32;
    const int og = fg, rg3 = rg;                    // L3: o-tile, j-group

    // zero strip (outside both cmx [0,16384) and h rows [0,19456))
    if (tid < 16) hB[ZOFF + tid] = (_Float16)0.f;

    const int sb = tid >> 4, dblk = tid & 15, d0 = dblk*8;  // staging role
    const _Float16* pfb = Pf + (size_t)sb*(TT*DD) + d0;

    const int bid = blockIdx.x;
    int it = (bid*33) >> 4;                          // contiguous t-major ranges
    const int hi = ((bid + 1)*33) >> 4;

    int cur_t = -1;
    f32x4 rz0 = (f32x4){-1e30f,-1e30f,-1e30f,-1e30f};  // z-domain max, b=ln
    f32x4 rz1 = rz0;                                    // b=16+ln
    half8 mi;                                           // carried cummax Pf[b,t..s0-1,d]
    __syncthreads();

    // flush z-max -> slot; LAST arriver for t finalizes it (split-K fixup).
    auto flush_t = [&](int ct) {
        float* scr = (float*)hB;                     // hB fully dead here
        if (rg3 == 1) {
            *(f32x4*)(scr + (og*64 + lane)*8)     = rz0;
            *(f32x4*)(scr + (og*64 + lane)*8 + 4) = rz1;
        }
        __syncthreads();
        int g2 = ct >> 2;
        int it_s = 2*g2*(65 - g2) + (ct - 4*g2)*(32 - g2);
        if (rg3 == 0) {
            f32x4 p0 = *(const f32x4*)(scr + (og*64 + lane)*8);
            f32x4 p1 = *(const f32x4*)(scr + (og*64 + lane)*8 + 4);
            #pragma unroll
            for (int i = 0; i < 4; ++i) {
                rz0[i] = fmaxf(rz0[i], p0[i]);
                rz1[i] = fmaxf(rz1[i], p1[i]);
            }
            int k = bid - bid_of(it_s);
            _Float16* sp = slots + ((size_t)ct*KSLOT + k)*2048;
            int o = og*16 + q*4;
            half4 z0, z1;
            #pragma unroll
            for (int i = 0; i < 4; ++i) { z0[i] = (_Float16)rz0[i]; z1[i] = (_Float16)rz1[i]; }
            *(half4*)(sp + ln*64 + o) = z0;
            *(half4*)(sp + (16+ln)*64 + o) = z1;
        }
        __syncthreads();                             // slot stores drained (vmcnt)
        if (tid == 0) {
            __threadfence();                         // release: wbl2
            int it_e = it_s + (32 - g2);
            int nT = bid_of(it_e - 1) - bid_of(it_s) + 1;
            unsigned r = atomicAdd(&tctr[ct], 1u);
            unsigned win = (r == (unsigned)(nT - 1)) ? 1u : 0u;
            if (win) __threadfence();                // acquire: inv L1/L2
            ((volatile unsigned*)scr)[0] = win;
            ((volatile int*)scr)[1] = nT;
        }
        __syncthreads();
        if (((volatile unsigned*)scr)[0]) {          // this block finalizes t=ct
            int nT = ((volatile int*)scr)[1];
            const _Float16* sb2 = slots + (size_t)ct*KSLOT*2048;
            int cell = tid * 4;                      // b*64 + o
            half4 h = *(const half4*)(sb2 + cell);
            f32x4 v;
            #pragma unroll
            for (int i = 0; i < 4; ++i) v[i] = (float)h[i];
            for (int k2 = 1; k2 < nT; ++k2) {
                half4 u = *(const half4*)(sb2 + k2*2048 + cell);
                #pragma unroll
                for (int i = 0; i < 4; ++i) v[i] = fmaxf(v[i], (float)u[i]);
            }
            f32x4 y;
            #pragma unroll
            for (int i = 0; i < 4; ++i) y[i] = 1.f / (1.f + __expf(-5.f * v[i]));
            *(f32x4*)(out + (size_t)(cell >> 6)*(TT*OO) + ct*OO + (cell & 63)) = y;
        }
        __syncthreads();                             // scr/cmx reusable
    };

    for (; it < hi; ++it) {
        // ---- decode item -> (t, c) ----
        int g = (int)((65.0f - sqrtf((float)(4225 - 2*it))) * 0.5f);
        if (g < 0) g = 0; if (g > 31) g = 31;
        while (g > 0 && 2*g*(65 - g) > it) --g;
        while (2*(g+1)*(65 - (g+1)) <= it) ++g;
        int rem = it - 2*g*(65 - g);
        int ntc = 32 - g;
        int t  = 4*g + rem/ntc;
        int c  = rem - (rem/ntc)*ntc;
        int s0 = t + 4*c;

        // ---- t-change: flush (+maybe finalize), reset + scan-init carry ----
        if (t != cur_t) {                            // block-uniform branch
            if (cur_t >= 0) flush_t(cur_t);
            cur_t = t;
            rz0 = (f32x4){-1e30f,-1e30f,-1e30f,-1e30f};
            rz1 = rz0;
            #pragma unroll
            for (int i = 0; i < 8; ++i) mi[i] = (_Float16)(-65504.0f);
            for (int s = t; s < s0; ++s)             // nonempty only at block start
                mi = h8max(mi, *(const half8*)(pfb + s*DD));
        }

        // ---- stage cmx: fold 4 steps onto carried mi ----
        #pragma unroll
        for (int j = 0; j < 4; ++j) {
            int s = s0 + j; if (s > 127) s = 127;    // dup of valid s=127, same b
            mi = h8max(mi, *(const half8*)(pfb + s*DD));
            int row = j*32 + sb;
            *(half8*)(cmx + row*128 + ((dblk ^ (row & 15))*8)) = mi;
        }
        __syncthreads();                             // [A]

        // ---- L1': z1^T = W1a^T @ cmx^T, init = PW + b1 (acc in regs) ----
        f32x4 aA[4], aB[4], aC[4];
        {
            const f32x4 bA1 = *(const f32x4*)(b1p + f0A + q*4);
            const f32x4 bB1 = *(const f32x4*)(b1p + f0B + q*4);
            #pragma unroll
            for (int rj = 0; rj < 4; ++rj) {
                int row = (rg*4 + rj)*16 + ln;           // j = row>>5, b = row&31
                int sj = s0 + (row >> 5);                // clamp s ONLY, preserve b
                if (sj > 127) sj = 127;
                int rowg = sj*32 + (row & 31);
                const _Float16* pwp = PW + (size_t)rowg*NP;
                half4 pA = *(const half4*)(pwp + f0A + q*4);
                half4 pB = *(const half4*)(pwp + f0B + q*4);
                aA[rj] = bA1; aB[rj] = bB1;
                #pragma unroll
                for (int i = 0; i < 4; ++i) { aA[rj][i] += (float)pA[i]; aB[rj][i] += (float)pB[i]; }
                if (has3) {
                    const f32x4 bC1 = *(const f32x4*)(b1p + f0C + q*4);
                    half4 pC = *(const half4*)(pwp + f0C + q*4);
                    aC[rj] = bC1;
                    #pragma unroll
                    for (int i = 0; i < 4; ++i) aC[rj][i] += (float)pC[i];
                }
            }
            #pragma unroll
            for (int kst = 0; kst < 4; ++kst) {
                half8 wA = *(const half8*)(W1t + (f0A+ln)*128 + kst*32 + q*8);
                half8 wB = *(const half8*)(W1t + (f0B+ln)*128 + kst*32 + q*8);
                half8 wC;
                if (has3) wC = *(const half8*)(W1t + (f0C+ln)*128 + kst*32 + q*8);
                int kb = kst*4 + q;
                #pragma unroll
                for (int rj = 0; rj < 4; ++rj) {
                    int row = (rg*4 + rj)*16 + ln;
                    half8 bf = *(const half8*)(cmx + row*128 + ((kb ^ (row & 15))*8));
                    aA[rj] = MFMA(wA, bf, aA[rj]);
                    aB[rj] = MFMA(wB, bf, aB[rj]);
                    if (has3) aC[rj] = MFMA(wC, bf, aC[rj]);
                }
            }
        }
        __syncthreads();                             // [A2] all cmx reads done
        #pragma unroll
        for (int rj = 0; rj < 4; ++rj) {             // relu -> h1 over hB
            int row = (rg*4 + rj)*16 + ln;
            half4 hA, hB4, hC;
            #pragma unroll
            for (int i = 0; i < 4; ++i) {
                hA[i]  = (_Float16)fmaxf(aA[rj][i], 0.f);
                hB4[i] = (_Float16)fmaxf(aB[rj][i], 0.f);
            }
            *(half4*)(hB + row*HSTR2 + f0A + q*4) = hA;
            *(half4*)(hB + row*HSTR2 + f0B + q*4) = hB4;
            if (has3) {
                #pragma unroll
                for (int i = 0; i < 4; ++i) hC[i] = (_Float16)fmaxf(aC[rj][i], 0.f);
                *(half4*)(hB + row*HSTR2 + f0C + q*4) = hC;
            }
        }
        __syncthreads();                             // [B]

        // ---- L2': z2^T = W2^T @ h1^T, relu (held in regs until [C]) ----
        half4 h2A[4], h2B[4], h2C[4];
        {
            const f32x4 bA2 = *(const f32x4*)(b2p + f0A + q*4);
            const f32x4 bB2 = *(const f32x4*)(b2p + f0B + q*4);
            #pragma unroll
            for (int rj = 0; rj < 4; ++rj) {
                aA[rj] = bA2; aB[rj] = bB2;
                if (has3) aC[rj] = *(const f32x4*)(b2p + f0C + q*4);
            }
            #pragma unroll
            for (int kst = 0; kst < 5; ++kst) {
                half8 wA = *(const half8*)(W2t + (f0A+ln)*160 + kst*32 + q*8);
                half8 wB = *(const half8*)(W2t + (f0B+ln)*160 + kst*32 + q*8);
                half8 wC;
                if (has3) wC = *(const half8*)(W2t + (f0C+ln)*160 + kst*32 + q*8);
                #pragma unroll
                for (int rj = 0; rj < 4; ++rj) {
                    int row = (rg*4 + rj)*16 + ln;
                    half8 bf = (kst < 4)
                        ? *(const half8*)(hB + row*HSTR2 + kst*32 + q*8)
                        : ((q < 2) ? *(const half8*)(hB + row*HSTR2 + 128 + q*8)
                                   : *(const half8*)zstrip);
                    aA[rj] = MFMA(wA, bf, aA[rj]);
                    aB[rj] = MFMA(wB, bf, aB[rj]);
                    if (has3) aC[rj] = MFMA(wC, bf, aC[rj]);
                }
            }
            #pragma unroll
            for (int rj = 0; rj < 4; ++rj) {
                #pragma unroll
                for (int i = 0; i < 4; ++i) {
                    h2A[rj][i] = (_Float16)fmaxf(aA[rj][i], 0.f);
                    h2B[rj][i] = (_Float16)fmaxf(aB[rj][i], 0.f);
                    if (has3) h2C[rj][i] = (_Float16)fmaxf(aC[rj][i], 0.f);
                }
            }
        }
        __syncthreads();                             // [C] all h1 reads done
        #pragma unroll
        for (int rj = 0; rj < 4; ++rj) {
            int row = (rg*4 + rj)*16 + ln;
            *(half4*)(hB + row*HSTR2 + f0A + q*4) = h2A[rj];
            *(half4*)(hB + row*HSTR2 + f0B + q*4) = h2B[rj];
            if (has3) *(half4*)(hB + row*HSTR2 + f0C + q*4) = h2C[rj];
        }
        __syncthreads();                             // [D]

        // ---- L3': z3^T = W3^T @ h2^T; merge into register z-max ----
        {
            const f32x4 bz3 = *(const f32x4*)(b3 + og*16 + q*4);
            f32x4 z[4];
            #pragma unroll
            for (int rj = 0; rj < 4; ++rj) z[rj] = bz3;
            #pragma unroll
            for (int kst = 0; kst < 5; ++kst) {
                half8 wO = *(const half8*)(W3t + (og*16+ln)*160 + kst*32 + q*8);
                #pragma unroll
                for (int rj = 0; rj < 4; ++rj) {
                    int row = (rg3*4 + rj)*16 + ln;
                    half8 bf = (kst < 4)
                        ? *(const half8*)(hB + row*HSTR2 + kst*32 + q*8)
                        : ((q < 2) ? *(const half8*)(hB + row*HSTR2 + 128 + q*8)
                                   : *(const half8*)zstrip);
                    z[rj] = MFMA(wO, bf, z[rj]);
                }
            }
            // rows encode (j = rg3*2 + (rj>>1), b = (rj&1)*16 + ln); clamped
            // rows duplicate (s=127, same b) -> merge all unconditionally
            #pragma unroll
            for (int i = 0; i < 4; ++i) {
                rz0[i] = fmaxf(rz0[i], fmaxf(z[0][i], z[2][i]));
                rz1[i] = fmaxf(rz1[i], fmaxf(z[1][i], z[3][i]));
            }
        }
        __syncthreads();                             // [E] protect hB for next item
    }

    flush_t(cur_t);                                  // final flush (+maybe finalize)
}

extern "C" void kernel_launch(void* const* d_in, const int* in_sizes, int n_in,
                              void* d_out, int out_size, void* d_ws, size_t ws_size,
                              hipStream_t stream) {
    const float* P  = (const float*)d_in[0];
    const float* W1 = (const float*)d_in[1];
    const float* b1 = (const float*)d_in[2];
    const float* W2 = (const float*)d_in[3];
    const float* b2 = (const float*)d_in[4];
    const float* W3 = (const float*)d_in[5];
    const float* b3 = (const float*)d_in[6];

    tll_prep<<<240, 256, 0, stream>>>(P, W1, b1, W2, b2, W3, (char*)d_ws);

    hipFuncSetAttribute((const void*)tll_main,
                        hipFuncAttributeMaxDynamicSharedMemorySize, 38944);
    tll_main<<<NBLK, 512, 38944, stream>>>(b3, (char*)d_ws, (float*)d_out);
}

// Round 13
// 188.055 us; speedup vs baseline: 1.3589x; 1.3589x over previous
//
#include <hip/hip_runtime.h>

// TemporalLogicLayer R13: balanced 9-units/wave GEMM split; revert R12 fixup.
// out[b,t,o] = max_{s>=t} sigmoid(5*(relu(relu([cummax(P[t..s])|P[s]]W1+b1)W2+b2)W3+b3))
//
// R12 post-mortem: in-loop finalize fixup (per-flush __threadfence + winner
// reduce) cost +42 us main for -8 us dispatch gap -> reverted (3 dispatches,
// nontemporal slot flush + tiny finalize kernel). Kept R12's coalesced PW prep.
//
// New in R13 — wave-balanced L1'/L2': previously 9 N-tiles split (3,2,2,2)
// over 4 f-groups x 2 r-groups: fg=0 waves did 50% more work per phase and
// every barrier waited for them; both r-groups loaded identical W fragments.
// Now wave w owns f-tile w (cols w*16..+15) for ALL 8 row-tiles, plus row-tile
// rt=w of the shared 9th tile (cols 128..143; its B-fragment equals the rt==w
// fragment). 9 MFMA-tile units per wave exactly; per-phase max MFMA 48->36
// (L1), 60->45 (L2); weight fragments per wave 3->2; acc regs 48->36 f32.
// L3' (4 o-tiles x 2 row-halves = balanced), staging, LDS overlay (38944 B,
// 4 blocks/CU), 1024-block grid, flush-to-slots: unchanged from R11.

#define TT 128
#define BB 32
#define DD 128
#define OO 64
#define NP 144
#define HSTR2 152
#define KSLOT 17
#define NBLK 1024
#define ZOFF (128*HSTR2)                            // zero strip, f16 offset 19456

typedef __attribute__((ext_vector_type(8))) _Float16 half8;
typedef __attribute__((ext_vector_type(4))) _Float16 half4;
typedef __attribute__((ext_vector_type(4))) float f32x4;

// ws layout (bytes)
#define W1T_OFF 0                                   // f16 [144][128] (K<128 half)
#define W2T_OFF (W1T_OFF + 144*128*2)               // f16 [144][160]
#define W3T_OFF (W2T_OFF + 144*160*2)               // f16 [64][160]
#define B1P_OFF (W3T_OFF + 64*160*2)                // f32 [144]
#define B2P_OFF (B1P_OFF + 144*4)                   // f32 [144]
#define PW_OFF  (B2P_OFF + 144*4)                   // f16 [4096][144]
#define PF_OFF  (PW_OFF + 4096*144*2)               // f16 [32][128][128]
#define SLOT_OFF (PF_OFF + 32*128*128*2)            // f16 [128][KSLOT][32][64]

#define MFMA(A, B, C) __builtin_amdgcn_mfma_f32_16x16x32_f16((A), (B), (C), 0, 0, 0)

__device__ __forceinline__ half8 h8max(half8 a, half8 b) {
    half8 r;
    #pragma unroll
    for (int i = 0; i < 8; ++i) r[i] = (a[i] > b[i]) ? a[i] : b[i];
    return r;
}

// largest bid with range_start(bid) = (bid*33)>>4 <= it   (1024-block partition)
__device__ __forceinline__ int bid_of(int it) {
    int bb = (16 * it) / 33;
    while ((((bb + 1) * 33) >> 4) <= it) ++bb;
    while (((bb * 33) >> 4) > it) --bb;
    return bb;
}

// ---------- prep (240 blocks x 256) ----------
__global__ void tll_prep(const float* __restrict__ P,
                         const float* __restrict__ W1, const float* __restrict__ b1,
                         const float* __restrict__ W2, const float* __restrict__ b2,
                         const float* __restrict__ W3, char* __restrict__ ws) {
    __shared__ _Float16 w1s[144 * 130];             // 37440 B (PW blocks only)
    const int blk = blockIdx.x, tid = threadIdx.x;
    if (blk < 144) {
        _Float16* W1t = (_Float16*)(ws + W1T_OFF);
        _Float16* W2t = (_Float16*)(ws + W2T_OFF);
        _Float16* W3t = (_Float16*)(ws + W3T_OFF);
        float*    b1p = (float*)(ws + B1P_OFF);
        float*    b2p = (float*)(ws + B2P_OFF);
        int idx = blk * 256 + tid;
        if (idx < 144*128) {                        // W1t[n][k] = W1[k][n], k<128
            int n = idx >> 7, k = idx & 127;
            W1t[idx] = (_Float16)((n < 132) ? W1[k*132 + n] : 0.f);
        }
        if (idx < 144*160) {                        // W2t[n][k] = W2[k][n]
            int n = idx / 160, k = idx - n*160;
            W2t[idx] = (_Float16)((n < 132 && k < 132) ? W2[k*132 + n] : 0.f);
        }
        if (idx < 64*160) {                         // W3t[o][k] = W3[k][o]
            int o = idx / 160, k = idx - o*160;
            W3t[idx] = (_Float16)((k < 132) ? W3[k*64 + o] : 0.f);
        }
        if (idx < 144) {
            b1p[idx] = (idx < 132) ? b1[idx] : 0.f;
            b2p[idx] = (idx < 132) ? b2[idx] : 0.f;
        }
    } else if (blk < 208) {
        // PW[row][n] = P[row] @ W1[128:256, :], row = s*32+b (coalesced+LDS)
        _Float16* PW = (_Float16*)(ws + PW_OFF);
        const int blkp = blk - 144;
        for (int i = tid; i < 128*132; i += 256) {  // i: k-major, n consecutive
            int k = i / 132, n = i - k*132;
            w1s[n*130 + k] = (_Float16)W1[(128 + k)*132 + n];
        }
        for (int i = tid; i < 12*130; i += 256) {   // zero pad n = 132..143
            int n = 132 + i/130, k = i - (i/130)*130;
            w1s[n*130 + k] = (_Float16)0.f;
        }
        __syncthreads();
        const int w = tid >> 6, lane = tid & 63;
        const int ln = lane & 15, q = lane >> 4;
        const int row = (blkp*4 + w)*16 + ln;       // 0..4095
        const int b_ = row & 31, s_ = row >> 5;
        const float* pp = P + b_*(TT*DD) + s_*DD;
        half8 Bf[4];
        #pragma unroll
        for (int kst = 0; kst < 4; ++kst) {
            f32x4 p0 = *(const f32x4*)(pp + kst*32 + q*8);
            f32x4 p1 = *(const f32x4*)(pp + kst*32 + q*8 + 4);
            half8 h;
            #pragma unroll
            for (int i = 0; i < 4; ++i) { h[i] = (_Float16)p0[i]; h[4+i] = (_Float16)p1[i]; }
            Bf[kst] = h;
        }
        for (int mt = 0; mt < 9; ++mt) {
            f32x4 acc = (f32x4){0.f, 0.f, 0.f, 0.f};
            #pragma unroll
            for (int kst = 0; kst < 4; ++kst) {
                half8 A = *(const half8*)&w1s[(mt*16 + ln)*130 + kst*32 + q*8];
                acc = MFMA(A, Bf[kst], acc);
            }
            half4 hv;
            #pragma unroll
            for (int i = 0; i < 4; ++i) hv[i] = (_Float16)acc[i];
            *(half4*)(PW + (size_t)row*NP + mt*16 + q*4) = hv;
        }
    } else {
        // Pf[b] = f16(P[b])
        _Float16* Pf = (_Float16*)(ws + PF_OFF);
        const int b = blk - 208;
        const f32x4* src = (const f32x4*)(P + (size_t)b * TT * DD);
        half4* dst = (half4*)(Pf + (size_t)b * TT * DD);
        for (int i = tid; i < TT*DD/4; i += 256) {
            f32x4 v = src[i];
            half4 h;
            #pragma unroll
            for (int j = 0; j < 4; ++j) h[j] = (_Float16)v[j];
            dst[i] = h;
        }
    }
}

// ---------- finalize (128 blocks x 512): out = sigmoid(5 * max_k slots) ----------
__global__ void tll_finalize(const char* __restrict__ ws, float* __restrict__ out) {
    const int t = blockIdx.x, tid = threadIdx.x;
    const int g = t >> 2;
    const int it_s = 2*g*(65 - g) + (t - 4*g)*(32 - g);
    const int it_e = it_s + (32 - g);
    const int n = bid_of(it_e - 1) - bid_of(it_s) + 1;     // <= KSLOT
    const _Float16* slots = (const _Float16*)(ws + SLOT_OFF) + (size_t)t * KSLOT * 2048;
    const int cell = tid * 4;                              // 2048 cells: b*64+o
    half4 h = *(const half4*)(slots + cell);
    f32x4 v;
    #pragma unroll
    for (int i = 0; i < 4; ++i) v[i] = (float)h[i];
    for (int k = 1; k < n; ++k) {
        half4 u = *(const half4*)(slots + k*2048 + cell);
        #pragma unroll
        for (int i = 0; i < 4; ++i) v[i] = fmaxf(v[i], (float)u[i]);
    }
    f32x4 y;
    #pragma unroll
    for (int i = 0; i < 4; ++i) y[i] = 1.f / (1.f + __expf(-5.f * v[i]));
    const int b = cell >> 6, o = cell & 63;
    *(f32x4*)(out + (size_t)b*(TT*OO) + t*OO + o) = y;
}

// ---------- main ----------
__global__ __launch_bounds__(512, 4) void tll_main(
    const float* __restrict__ b3, char* __restrict__ ws)
{
    extern __shared__ char smem[];
    _Float16* hB  = (_Float16*)smem;                // overlay: cmx[128][128]sw /
    _Float16* cmx = hB;                             //          h[128][152]
    const _Float16* zstrip = hB + ZOFF;             // 32 B zeros (kst=4, q>=2)

    const _Float16* W1t = (const _Float16*)(ws + W1T_OFF);
    const _Float16* W2t = (const _Float16*)(ws + W2T_OFF);
    const _Float16* W3t = (const _Float16*)(ws + W3T_OFF);
    const float*    b1p = (const float*)(ws + B1P_OFF);
    const float*    b2p = (const float*)(ws + B2P_OFF);
    const _Float16* PW  = (const _Float16*)(ws + PW_OFF);
    const _Float16* Pf  = (const _Float16*)(ws + PF_OFF);
    _Float16*       slots = (_Float16*)(ws + SLOT_OFF);

    const int tid = threadIdx.x, w = tid >> 6, lane = tid & 63;
    const int ln = lane & 15, q = lane >> 4;
    const int fw0 = w*16;                           // this wave's f-tile cols
    const int og = w >> 1, rg3 = w & 1;             // L3 + flush roles (as R11)

    // zero strip (outside both cmx [0,16384) and h rows [0,19456))
    if (tid < 16) hB[ZOFF + tid] = (_Float16)0.f;

    const int sb = tid >> 4, dblk = tid & 15, d0 = dblk*8;  // staging role
    const _Float16* pfb = Pf + (size_t)sb*(TT*DD) + d0;

    const int bid = blockIdx.x;
    int it = (bid*33) >> 4;                          // contiguous t-major ranges
    const int hi = ((bid + 1)*33) >> 4;

    int cur_t = -1;
    f32x4 rz0 = (f32x4){-1e30f,-1e30f,-1e30f,-1e30f};  // z-domain max, b=ln
    f32x4 rz1 = rz0;                                    // b=16+ln
    half8 mi;                                           // carried cummax Pf[b,t..s0-1,d]
    __syncthreads();

    for (; it < hi; ++it) {
        // ---- decode item -> (t, c) ----
        int g = (int)((65.0f - sqrtf((float)(4225 - 2*it))) * 0.5f);
        if (g < 0) g = 0; if (g > 31) g = 31;
        while (g > 0 && 2*g*(65 - g) > it) --g;
        while (2*(g+1)*(65 - (g+1)) <= it) ++g;
        int rem = it - 2*g*(65 - g);
        int ntc = 32 - g;
        int t  = 4*g + rem/ntc;
        int c  = rem - (rem/ntc)*ntc;
        int s0 = t + 4*c;

        // ---- t-change: flush z-max to slot, reset + scan-init carry ----
        if (t != cur_t) {                            // block-uniform branch
            if (cur_t >= 0) {
                float* scr = (float*)hB;             // hB fully dead here
                if (rg3 == 1) {
                    *(f32x4*)(scr + (og*64 + lane)*8)     = rz0;
                    *(f32x4*)(scr + (og*64 + lane)*8 + 4) = rz1;
                }
                __syncthreads();
                if (rg3 == 0) {
                    f32x4 p0 = *(const f32x4*)(scr + (og*64 + lane)*8);
                    f32x4 p1 = *(const f32x4*)(scr + (og*64 + lane)*8 + 4);
                    #pragma unroll
                    for (int i = 0; i < 4; ++i) {
                        rz0[i] = fmaxf(rz0[i], p0[i]);
                        rz1[i] = fmaxf(rz1[i], p1[i]);
                    }
                    int k = bid - bid_of(2*(cur_t >> 2)*(65 - (cur_t >> 2))
                                         + (cur_t - 4*(cur_t >> 2))*(32 - (cur_t >> 2)));
                    _Float16* sp = slots + ((size_t)cur_t*KSLOT + k)*2048;
                    int o = og*16 + q*4;
                    half4 z0, z1;
                    #pragma unroll
                    for (int i = 0; i < 4; ++i) { z0[i] = (_Float16)rz0[i]; z1[i] = (_Float16)rz1[i]; }
                    __builtin_nontemporal_store(z0, (half4*)(sp + ln*64 + o));
                    __builtin_nontemporal_store(z1, (half4*)(sp + (16+ln)*64 + o));
                }
                __syncthreads();                     // protect scr before staging
            }
            cur_t = t;
            rz0 = (f32x4){-1e30f,-1e30f,-1e30f,-1e30f};
            rz1 = rz0;
            #pragma unroll
            for (int i = 0; i < 8; ++i) mi[i] = (_Float16)(-65504.0f);
            for (int s = t; s < s0; ++s)             // nonempty only at block start
                mi = h8max(mi, *(const half8*)(pfb + s*DD));
        }

        // ---- stage cmx: fold 4 steps onto carried mi ----
        #pragma unroll
        for (int j = 0; j < 4; ++j) {
            int s = s0 + j; if (s > 127) s = 127;    // dup of valid s=127, same b
            mi = h8max(mi, *(const half8*)(pfb + s*DD));
            int row = j*32 + sb;
            *(half8*)(cmx + row*128 + ((dblk ^ (row & 15))*8)) = mi;
        }
        __syncthreads();                             // [A]

        // ---- L1': balanced — wave w: f-tile w x 8 row-tiles + S-unit(rt=w) ----
        f32x4 acc[8], accS;
        {
            const f32x4 b1w = *(const f32x4*)(b1p + fw0 + q*4);
            const f32x4 b1S = *(const f32x4*)(b1p + 128 + q*4);
            #pragma unroll
            for (int rt = 0; rt < 8; ++rt) {
                int row = rt*16 + ln;                    // j = row>>5, b = row&31
                int sj = s0 + (row >> 5);                // clamp s ONLY, preserve b
                if (sj > 127) sj = 127;
                int rowg = sj*32 + (row & 31);
                half4 p = *(const half4*)(PW + (size_t)rowg*NP + fw0 + q*4);
                acc[rt] = b1w;
                #pragma unroll
                for (int i = 0; i < 4; ++i) acc[rt][i] += (float)p[i];
                if (rt == w) {
                    half4 pS = *(const half4*)(PW + (size_t)rowg*NP + 128 + q*4);
                    accS = b1S;
                    #pragma unroll
                    for (int i = 0; i < 4; ++i) accS[i] += (float)pS[i];
                }
            }
            #pragma unroll
            for (int kst = 0; kst < 4; ++kst) {
                half8 wA = *(const half8*)(W1t + (fw0+ln)*128 + kst*32 + q*8);
                half8 wS = *(const half8*)(W1t + (128+ln)*128 + kst*32 + q*8);
                int kb = kst*4 + q;
                #pragma unroll
                for (int rt = 0; rt < 8; ++rt) {
                    int row = rt*16 + ln;                // row & 15 == ln
                    half8 bf = *(const half8*)(cmx + row*128 + ((kb ^ ln)*8));
                    acc[rt] = MFMA(wA, bf, acc[rt]);
                    if (rt == w) accS = MFMA(wS, bf, accS);
                }
            }
        }
        __syncthreads();                             // [A2] all cmx reads done
        #pragma unroll
        for (int rt = 0; rt < 8; ++rt) {             // relu -> h1 over hB
            int row = rt*16 + ln;
            half4 hv;
            #pragma unroll
            for (int i = 0; i < 4; ++i) hv[i] = (_Float16)fmaxf(acc[rt][i], 0.f);
            *(half4*)(hB + row*HSTR2 + fw0 + q*4) = hv;
        }
        {
            int row = w*16 + ln;
            half4 hv;
            #pragma unroll
            for (int i = 0; i < 4; ++i) hv[i] = (_Float16)fmaxf(accS[i], 0.f);
            *(half4*)(hB + row*HSTR2 + 128 + q*4) = hv;
        }
        __syncthreads();                             // [B]

        // ---- L2': same balanced split, K=160 (zstrip covers cols 144..159) ----
        half4 h2[8], h2S;
        {
            const f32x4 b2w = *(const f32x4*)(b2p + fw0 + q*4);
            const f32x4 b2S = *(const f32x4*)(b2p + 128 + q*4);
            #pragma unroll
            for (int rt = 0; rt < 8; ++rt) acc[rt] = b2w;
            accS = b2S;
            #pragma unroll
            for (int kst = 0; kst < 5; ++kst) {
                half8 wA = *(const half8*)(W2t + (fw0+ln)*160 + kst*32 + q*8);
                half8 wS = *(const half8*)(W2t + (128+ln)*160 + kst*32 + q*8);
                #pragma unroll
                for (int rt = 0; rt < 8; ++rt) {
                    int row = rt*16 + ln;
                    half8 bf = (kst < 4)
                        ? *(const half8*)(hB + row*HSTR2 + kst*32 + q*8)
                        : ((q < 2) ? *(const half8*)(hB + row*HSTR2 + 128 + q*8)
                                   : *(const half8*)zstrip);
                    acc[rt] = MFMA(wA, bf, acc[rt]);
                    if (rt == w) accS = MFMA(wS, bf, accS);
                }
            }
            #pragma unroll
            for (int rt = 0; rt < 8; ++rt)
                #pragma unroll
                for (int i = 0; i < 4; ++i) h2[rt][i] = (_Float16)fmaxf(acc[rt][i], 0.f);
            #pragma unroll
            for (int i = 0; i < 4; ++i) h2S[i] = (_Float16)fmaxf(accS[i], 0.f);
        }
        __syncthreads();                             // [C] all h1 reads done
        #pragma unroll
        for (int rt = 0; rt < 8; ++rt) {
            int row = rt*16 + ln;
            *(half4*)(hB + row*HSTR2 + fw0 + q*4) = h2[rt];
        }
        *(half4*)(hB + (w*16 + ln)*HSTR2 + 128 + q*4) = h2S;
        __syncthreads();                             // [D]

        // ---- L3': z3^T = W3^T @ h2^T (4 o-tiles x 2 row-halves, balanced) ----
        {
            const f32x4 bz3 = *(const f32x4*)(b3 + og*16 + q*4);
            f32x4 z[4];
            #pragma unroll
            for (int rj = 0; rj < 4; ++rj) z[rj] = bz3;
            #pragma unroll
            for (int kst = 0; kst < 5; ++kst) {
                half8 wO = *(const half8*)(W3t + (og*16+ln)*160 + kst*32 + q*8);
                #pragma unroll
                for (int rj = 0; rj < 4; ++rj) {
                    int row = (rg3*4 + rj)*16 + ln;
                    half8 bf = (kst < 4)
                        ? *(const half8*)(hB + row*HSTR2 + kst*32 + q*8)
                        : ((q < 2) ? *(const half8*)(hB + row*HSTR2 + 128 + q*8)
                                   : *(const half8*)zstrip);
                    z[rj] = MFMA(wO, bf, z[rj]);
                }
            }
            // rows encode (j = rg3*2 + (rj>>1), b = (rj&1)*16 + ln); clamped
            // rows duplicate (s=127, same b) -> merge all unconditionally
            #pragma unroll
            for (int i = 0; i < 4; ++i) {
                rz0[i] = fmaxf(rz0[i], fmaxf(z[0][i], z[2][i]));
                rz1[i] = fmaxf(rz1[i], fmaxf(z[1][i], z[3][i]));
            }
        }
        __syncthreads();                             // [E] protect hB for next item
    }

    // ---- final flush ----
    {
        float* scr = (float*)hB;
        if (rg3 == 1) {
            *(f32x4*)(scr + (og*64 + lane)*8)     = rz0;
            *(f32x4*)(scr + (og*64 + lane)*8 + 4) = rz1;
        }
        __syncthreads();
        if (rg3 == 0) {
            f32x4 p0 = *(const f32x4*)(scr + (og*64 + lane)*8);
            f32x4 p1 = *(const f32x4*)(scr + (og*64 + lane)*8 + 4);
            #pragma unroll
            for (int i = 0; i < 4; ++i) {
                rz0[i] = fmaxf(rz0[i], p0[i]);
                rz1[i] = fmaxf(rz1[i], p1[i]);
            }
            int k = bid - bid_of(2*(cur_t >> 2)*(65 - (cur_t >> 2))
                                 + (cur_t - 4*(cur_t >> 2))*(32 - (cur_t >> 2)));
            _Float16* sp = slots + ((size_t)cur_t*KSLOT + k)*2048;
            int o = og*16 + q*4;
            half4 z0, z1;
            #pragma unroll
            for (int i = 0; i < 4; ++i) { z0[i] = (_Float16)rz0[i]; z1[i] = (_Float16)rz1[i]; }
            __builtin_nontemporal_store(z0, (half4*)(sp + ln*64 + o));
            __builtin_nontemporal_store(z1, (half4*)(sp + (16+ln)*64 + o));
        }
    }
}

extern "C" void kernel_launch(void* const* d_in, const int* in_sizes, int n_in,
                              void* d_out, int out_size, void* d_ws, size_t ws_size,
                              hipStream_t stream) {
    const float* P  = (const float*)d_in[0];
    const float* W1 = (const float*)d_in[1];
    const float* b1 = (const float*)d_in[2];
    const float* W2 = (const float*)d_in[3];
    const float* b2 = (const float*)d_in[4];
    const float* W3 = (const float*)d_in[5];
    const float* b3 = (const float*)d_in[6];

    tll_prep<<<240, 256, 0, stream>>>(P, W1, b1, W2, b2, W3, (char*)d_ws);

    hipFuncSetAttribute((const void*)tll_main,
                        hipFuncAttributeMaxDynamicSharedMemorySize, 38944);
    tll_main<<<NBLK, 512, 38944, stream>>>(b3, (char*)d_ws);

    tll_finalize<<<128, 512, 0, stream>>>((const char*)d_ws, (float*)d_out);
}